// Round 6
// baseline (415.451 us; speedup 1.0000x reference)
//
#include <hip/hip_runtime.h>
#include <cstdint>
#include <cstddef>

// ---------------------------------------------------------------------------
// DifferentialAttention on MI355X (gfx950), bf16 MFMA pipeline.
// B=2 T=2048 D=2048 H=16 HD=128 HHD=64  SCALE=1/8
// R12: gemm256_qkv rebuilt on the m201 geometry (the piece R7 missed):
//   256x256 tile, 8 waves with PER-WAVE 128x64 output -> B-frags loaded once
//   per K-step and HELD IN REGISTERS across the 2 quadrant phases.
//   LDS-read volume drops to 0.375 reads/MFMA (was 0.5) and per-phase LDS
//   pipe time ~190cy vs matrix 155cy (was 350 vs 155 -> LDS-bound).
//   BK=32, 3-deep K-step ring (96KB): read slot j%3, stage j+2 -> (j+2)%3
//   (occupant = K-step j-1's data, fully read before j's opening barrier).
//   vmcnt(4) once per K-step at P1 tail: in-flight = (j+1)'s 4 + (j+2)'s 4;
//   leaves (j+2)'s 4, confirms (j+1)'s 4 = exactly what j+1 reads.
//   [256][32] LDS rows with chunk-XOR (lh ^ ((li>>3)&1)<<1): 4-way b128
//   aliasing (free) instead of 8-way (R6's 1.26e7 conflicts); source
//   pre-swizzled, global_load_lds stays linear.
// ---------------------------------------------------------------------------

typedef unsigned short u16;
typedef __bf16 bf16x8 __attribute__((ext_vector_type(8)));
typedef float f32x4 __attribute__((ext_vector_type(4)));

#define LOG2E 1.44269504088896340736f
// p = exp(s*0.125 - 8) = exp2(s * KS - CB); fixed bias 8 replaces running max
#define KS 0.18033688011112042f   /* 0.125 * log2(e) */
#define CB 11.541560327111707f    /* 8.0  * log2(e) */

__device__ __forceinline__ u16 f2bu(float f) {
  unsigned int x = __float_as_uint(f);
  x += 0x7fffu + ((x >> 16) & 1u);   // round-to-nearest-even (finite inputs)
  return (u16)(x >> 16);
}

// global -> LDS staging, 16B per lane. lds_uniform must be wave-uniform;
// hardware places lane's data at lds_uniform + lane*16.
__device__ __forceinline__ void stage16(const void* g, void* lds_uniform, int lane) {
#if defined(__has_builtin) && __has_builtin(__builtin_amdgcn_global_load_lds)
  (void)lane;
  __builtin_amdgcn_global_load_lds(
      (__attribute__((address_space(1))) void*)(g),
      (__attribute__((address_space(3))) void*)(lds_uniform), 16, 0, 0);
#else
  *(uint4*)((char*)lds_uniform + lane * 16) = *(const uint4*)g;
#endif
}

// one 256-row x 32-elem K-step tile slice: two 512-lane DMAs (rows 0-127,
// 128-255). Explicit +128*4096 global / +8192 LDS, offset imm always 0.
__device__ __forceinline__ void stageK(const char* g, char* lds_u) {
#if defined(__has_builtin) && __has_builtin(__builtin_amdgcn_global_load_lds)
  __builtin_amdgcn_global_load_lds(
      (__attribute__((address_space(1))) void*)g,
      (__attribute__((address_space(3))) void*)lds_u, 16, 0, 0);
  __builtin_amdgcn_global_load_lds(
      (__attribute__((address_space(1))) void*)(g + (size_t)128 * 4096),
      (__attribute__((address_space(3))) void*)(lds_u + 8192), 16, 0, 0);
#endif
}

// ---------------------------------------------------------------------------
// fp32 -> bf16 elementwise (vectorized), exact-grid
// ---------------------------------------------------------------------------
__global__ void f32_to_bf16_k(const float* __restrict__ in, u16* __restrict__ out, int n4) {
  int i = blockIdx.x * blockDim.x + threadIdx.x;
  if (i < n4) {
    float4 v = ((const float4*)in)[i];
    ushort4 u;
    u.x = f2bu(v.x); u.y = f2bu(v.y); u.z = f2bu(v.z); u.w = f2bu(v.w);
    ((ushort4*)out)[i] = u;
  }
}

// ---------------------------------------------------------------------------
// fp32 (R x C) -> bf16 transposed (C x R), 32x32 LDS tiles
// ---------------------------------------------------------------------------
__global__ void transpose_f32_bf16(const float* __restrict__ in, u16* __restrict__ out,
                                   int R, int C) {
  __shared__ u16 tile[32][33];
  const int tx = threadIdx.x & 31, ty = threadIdx.x >> 5; // 32 x 8
  const int c0 = blockIdx.x * 32, r0 = blockIdx.y * 32;
#pragma unroll
  for (int i = 0; i < 32; i += 8)
    tile[ty + i][tx] = f2bu(in[(size_t)(r0 + ty + i) * C + c0 + tx]);
  __syncthreads();
#pragma unroll
  for (int i = 0; i < 32; i += 8)
    out[(size_t)(c0 + ty + i) * R + r0 + tx] = tile[tx][ty + i];
}

// ---------------------------------------------------------------------------
// Legacy 128x128 GEMM (m97-structure) — used for out-proj and fallback path.
// C(M,N) = A(M,K) @ BT(N,K)^T   all bf16 in, fp32 accumulate.
// MODE 0: bf16 natural   MODE 1: fp32 natural
// MODE 2: bf16 V-transpose -> out[((b*16+h)*128+d)*2048 + t]
// ---------------------------------------------------------------------------
template <int MODE>
__global__ void gemm_bt(const u16* __restrict__ A, const u16* __restrict__ BT,
                        void* __restrict__ C, u16* __restrict__ C2,
                        int Mdim, int Ndim, int Kdim) {
  __shared__ __align__(16) u16 As[128 * 32];
  __shared__ __align__(16) u16 Bs[128 * 32];
  const int tid = threadIdx.x;
  const int lane = tid & 63;
  const int w = tid >> 6;
  const int wm = w & 1, wn = w >> 1;
  const int li = lane & 15, lh = lane >> 4;
  const int m0 = blockIdx.x * 128;
  const int n0 = blockIdx.y * 128;

  const f32x4 fzero = {0.f, 0.f, 0.f, 0.f};
  f32x4 acc[4][4];
#pragma unroll
  for (int i = 0; i < 4; ++i)
#pragma unroll
    for (int jj = 0; jj < 4; ++jj) acc[i][jj] = fzero;

  for (int k0 = 0; k0 < Kdim; k0 += 32) {
#pragma unroll
    for (int i = 0; i < 2; ++i) {
      const int c = i * 256 + w * 64 + lane;
      stage16(A + (size_t)(m0 + (c >> 2)) * Kdim + k0 + ((c & 3) << 3),
              (char*)As + (size_t)(i * 256 + w * 64) * 16, lane);
      stage16(BT + (size_t)(n0 + (c >> 2)) * Kdim + k0 + ((c & 3) << 3),
              (char*)Bs + (size_t)(i * 256 + w * 64) * 16, lane);
    }
    __syncthreads();

    bf16x8 af[4], bfr[4];
#pragma unroll
    for (int mt = 0; mt < 4; ++mt)
      af[mt] = *(const bf16x8*)&As[(wm * 64 + mt * 16 + li) * 32 + lh * 8];
#pragma unroll
    for (int nt = 0; nt < 4; ++nt)
      bfr[nt] = *(const bf16x8*)&Bs[(wn * 64 + nt * 16 + li) * 32 + lh * 8];
#pragma unroll
    for (int mt = 0; mt < 4; ++mt)
#pragma unroll
      for (int nt = 0; nt < 4; ++nt)
        acc[mt][nt] = __builtin_amdgcn_mfma_f32_16x16x32_bf16(af[mt], bfr[nt], acc[mt][nt], 0, 0, 0);
    __syncthreads();
  }

  // epilogue: C/D layout col = lane&15, row = (lane>>4)*4 + reg
#pragma unroll
  for (int mt = 0; mt < 4; ++mt) {
#pragma unroll
    for (int nt = 0; nt < 4; ++nt) {
      const int mb = m0 + wm * 64 + mt * 16 + lh * 4; // 4 consecutive rows
      const int n = n0 + wn * 64 + nt * 16 + li;
      if (MODE == 0) {
        u16* o = (u16*)C;
#pragma unroll
        for (int r = 0; r < 4; ++r)
          o[(size_t)(mb + r) * Ndim + n] = f2bu(acc[mt][nt][r]);
      } else if (MODE == 1) {
        float* o = (float*)C;
#pragma unroll
        for (int r = 0; r < 4; ++r)
          o[(size_t)(mb + r) * Ndim + n] = acc[mt][nt][r];
      } else {
        u16* o = (u16*)C;
        const int bb = mb >> 11, t = mb & 2047;
        const int hh = n >> 7, d = n & 127;
        ushort4 u;
        u.x = f2bu(acc[mt][nt][0]);
        u.y = f2bu(acc[mt][nt][1]);
        u.z = f2bu(acc[mt][nt][2]);
        u.w = f2bu(acc[mt][nt][3]);
        *(ushort4*)&o[((size_t)((bb * 16 + hh) * 128 + d) << 11) + t] = u;
      }
    }
  }
}

// ---------------------------------------------------------------------------
// 256x256 fused-QKV GEMM, m201 geometry. A(4096,2048) @ BT(6144,2048)^T.
// Grid 384 = 16 mtiles x 24 ntiles (1.5 rounds; per-phase efficiency is the
// lever, not rounds — R9). N-chunk [0,2048)->Q; [2048,4096)->K; [4096,6144)
// ->V per-head transposed into C2.
//
// 8 waves: wm=w>>2 (128-row half), wn=w&3 (64-col quarter). Per-wave output
// 128x64 = acc[8][4]. K-step BK=32: per wave 32 MFMA over 2 phases:
//   P0: quadrants 0-1 (frag-rows 0-3): 4 A-reads + 4 B-reads (B HELD in regs)
//       + stage A(j+2)
//   P1: quadrants 2-3 (frag-rows 4-7): 4 A-reads (B reused from P0)
//       + stage B(j+2); tail vmcnt(4); barrier
// Ring: 3 slots x 16KB per matrix (96KB). Read slot j%3; stage (j+2)%3 whose
// occupant (j-1) was fully read before j's opening barrier. vmcnt(4) at j's
// P1 tail: in-flight = (j+1)'s 4 instrs + (j+2)'s 4; confirms (j+1)'s ✓.
// Prologue: A0,B0,A1,B1 (8 instrs), vmcnt(4) confirms A0,B0.
// Main j=0..59 unrolled by 3 (slots compile-time); j=60,61 stage 62,63;
// j=62 vmcnt(0); j=63 clean.
// LDS [256][32] 64B rows, chunk-XOR swizzle (4-way b128 aliasing = free).
// ---------------------------------------------------------------------------
__global__ __launch_bounds__(512, 1)
void gemm256_qkv(const u16* __restrict__ A, const u16* __restrict__ BT,
                 u16* __restrict__ C, u16* __restrict__ C2, int /*Kdim*/) {
  __shared__ __align__(16) u16 As[3][256][32];   // 48KB, K-step ring
  __shared__ __align__(16) u16 Bs[3][256][32];   // 48KB, K-step ring

  const int tid = threadIdx.x;
  const int lane = tid & 63;
  const int w = tid >> 6;              // 0..7
  const int wm = w >> 2;               // 128-row half of the 256-row tile
  const int wn = w & 3;                // 64-col quarter
  const int li = lane & 15, lh = lane >> 4;
  const int lhx8 = (lh ^ (((li >> 3) & 1) << 1)) * 8;   // swizzled k-chunk

  // XCD-aware swizzle: xcd owns ntiles [3*xcd, 3*xcd+2], mt-major inside.
  const int bid = blockIdx.x;          // 0..383
  const int xcd = bid & 7;
  const int local = bid >> 3;          // 0..47
  const int mtile = local / 3;         // 0..15
  const int ntile = xcd * 3 + (local % 3);  // 0..23
  const int m0 = mtile * 256, n0 = ntile * 256;

  // per-lane staging source offset: LDS lane slot (row=tid>>2, chunk=tid&3)
  // maps to global (row, chunk ^ ((row>>3)&1)<<1)  [pre-swizzle involution]
  const int srow = tid >> 2;                        // 0..127
  const int schk = (tid & 3) ^ (((tid >> 5) & 1) << 1);
  const size_t soff = (size_t)srow * 4096 + (size_t)schk * 16;  // bytes

  const char* pA = (const char*)A  + (size_t)m0 * 4096 + soff;
  const char* pB = (const char*)BT + (size_t)n0 * 4096 + soff;

  const char* aB = (const char*)As + (size_t)(wm * 128 + li) * 64 + lhx8 * 2;
  const char* bB = (const char*)Bs + (size_t)(wn * 64 + li) * 64 + lhx8 * 2;
  char* const AsW = (char*)As + w * 1024;
  char* const BsW = (char*)Bs + w * 1024;

#define STAGE_A(SLOT) { stageK(pA, AsW + (SLOT) * 16384); pA += 64; }
#define STAGE_B(SLOT) { stageK(pB, BsW + (SLOT) * 16384); pB += 64; }

  const f32x4 fzero = {0.f, 0.f, 0.f, 0.f};
  f32x4 acc[8][4];
#pragma unroll
  for (int i = 0; i < 8; ++i)
#pragma unroll
    for (int jj = 0; jj < 4; ++jj) acc[i][jj] = fzero;

  // prologue: A0,B0,A1,B1 (8 instrs); vmcnt(4) confirms A0,B0.
  STAGE_A(0); STAGE_B(0); STAGE_A(1); STAGE_B(1);
  asm volatile("s_waitcnt vmcnt(4)" ::: "memory");
  __builtin_amdgcn_s_barrier();
  asm volatile("" ::: "memory");

  bf16x8 bfc[4];   // B-frags: loaded at P0, reused at P1 (held in VGPRs)

#define QPH(SLOT, P, LOADB, STAGES, TAIL)                                      \
  {                                                                            \
    bf16x8 af[4];                                                              \
    _Pragma("unroll")                                                          \
    for (int mq = 0; mq < 4; ++mq)                                             \
      af[mq] = *(const bf16x8*)(aB + (SLOT) * 16384 + ((P) * 4 + mq) * 1024);  \
    if (LOADB) {                                                               \
      _Pragma("unroll")                                                        \
      for (int nt = 0; nt < 4; ++nt)                                           \
        bfc[nt] = *(const bf16x8*)(bB + (SLOT) * 16384 + nt * 1024);           \
    }                                                                          \
    STAGES;                                                                    \
    __builtin_amdgcn_s_barrier();                                              \
    asm volatile("" ::: "memory");                                             \
    __builtin_amdgcn_s_setprio(1);                                             \
    _Pragma("unroll")                                                          \
    for (int mq = 0; mq < 4; ++mq) {                                           \
      _Pragma("unroll")                                                        \
      for (int nt = 0; nt < 4; ++nt)                                           \
        acc[(P) * 4 + mq][nt] = __builtin_amdgcn_mfma_f32_16x16x32_bf16(       \
            af[mq], bfc[nt], acc[(P) * 4 + mq][nt], 0, 0, 0);                  \
    }                                                                          \
    __builtin_amdgcn_s_setprio(0);                                             \
    TAIL;                                                                      \
    __builtin_amdgcn_s_barrier();                                              \
    asm volatile("" ::: "memory");                                             \
  }

#define KSTEP_MAIN(J3)                                                         \
  QPH((J3), 0, 1, { STAGE_A(((J3) + 2) % 3); }, ((void)0))                     \
  QPH((J3), 1, 0, { STAGE_B(((J3) + 2) % 3); },                                \
      asm volatile("s_waitcnt vmcnt(4)" ::: "memory"))

  for (int t3 = 0; t3 < 20; ++t3) {    // K-steps 0..59
    KSTEP_MAIN(0)
    KSTEP_MAIN(1)
    KSTEP_MAIN(2)
  }
  KSTEP_MAIN(0)                        // j=60, stages 62 -> slot 2
  KSTEP_MAIN(1)                        // j=61, stages 63 -> slot 0
  // j=62: slot 2, no stages; vmcnt(0) confirms 63's 4 instrs.
  QPH(2, 0, 1, ((void)0), ((void)0))
  QPH(2, 1, 0, ((void)0), asm volatile("s_waitcnt vmcnt(0)" ::: "memory"))
  // j=63: slot 0, nothing in flight.
  QPH(0, 0, 1, ((void)0), ((void)0))
  QPH(0, 1, 0, ((void)0), ((void)0))

#undef QPH
#undef KSTEP_MAIN
#undef STAGE_A
#undef STAGE_B

  // epilogue: C/D layout col = lane&15, row = (lane>>4)*4 + reg
  const int proj = n0 >> 11;                 // 0=Q, 1=K, 2=V (block-uniform)
  const int nB = (n0 & 2047) + wn * 64;
  const int mB = m0 + wm * 128;
#pragma unroll
  for (int mt = 0; mt < 8; ++mt) {
#pragma unroll
    for (int nt = 0; nt < 4; ++nt) {
      const int mb = mB + mt * 16 + lh * 4;  // 4 consecutive rows
      const int n = nB + nt * 16 + li;
      if (proj < 2) {
        u16* o = C + (size_t)proj * 4096 * 2048;
#pragma unroll
        for (int r = 0; r < 4; ++r)
          o[(size_t)(mb + r) * 2048 + n] = f2bu(acc[mt][nt][r]);
      } else {
        const int bb = mb >> 11, t = mb & 2047;
        const int hh = n >> 7, d = n & 127;
        ushort4 u;
        u.x = f2bu(acc[mt][nt][0]);
        u.y = f2bu(acc[mt][nt][1]);
        u.z = f2bu(acc[mt][nt][2]);
        u.w = f2bu(acc[mt][nt][3]);
        *(ushort4*)&C2[((size_t)((bb * 16 + hh) * 128 + d) << 11) + t] = u;
      }
    }
  }
}

// ---------------------------------------------------------------------------
// Flash differential attention: paired q-tiles, double-buffered DMA.
// grid = 512 (1D): bh = idx&31 (XCD pin), pair = idx>>5 in [0,16).
// Block processes q-tile `pair` then q-tile `31-pair` -> 33 iters uniform.
// Per iter: one barrier; prefetch K/V(j+1) into alt buffer right after it.
// Wave w owns Q rows t0+w*16..+15; P round-trip is wave-private (no barrier).
// Fixed-bias softmax; l reduced once per phase. LDS 80KB -> 2 blocks/CU.
// ---------------------------------------------------------------------------
__device__ __forceinline__ void stage_kv(const u16* __restrict__ kbase,
                                         const u16* __restrict__ vbase, int j,
                                         u16* ksBuf, u16* vsBuf, int w, int lane) {
  const int kst_r = lane >> 4, kst_c = lane & 15;
  const int vst_r = lane >> 3, vst_c = lane & 7;
#pragma unroll
  for (int i = 0; i < 4; ++i) {
    const int t = w * 4 + i;
    const int srow = t * 4 + kst_r;
    const int scb = kst_c ^ (srow & 7);
    stage16(kbase + (size_t)(j * 64 + srow) * 2048 + scb * 8,
            (char*)ksBuf + t * 1024, lane);
    const int drow = t * 8 + vst_r;
    const int dcb = vst_c ^ (drow & 7);
    stage16(vbase + (size_t)drow * 2048 + j * 64 + dcb * 8,
            (char*)vsBuf + t * 1024, lane);
  }
}

__global__ __launch_bounds__(256, 2)
void diff_attn(const u16* __restrict__ Q, const u16* __restrict__ K,
               const u16* __restrict__ VT, const float* __restrict__ lamin,
               u16* __restrict__ AO) {
  __shared__ __align__(16) u16 Ks[2][64 * 128];   // [s][c], col-block swizzled
  __shared__ __align__(16) u16 Vs[2][128 * 64];   // [d][s], col-block swizzled
  __shared__ __align__(16) u16 Ps1[64 * 64];
  __shared__ __align__(16) u16 Ps2[64 * 64];

  const int tid = threadIdx.x, lane = tid & 63, w = tid >> 6;
  const int li = lane & 15, lh = lane >> 4;
  const int bh = blockIdx.x & 31, pair = blockIdx.x >> 5;
  const int b = bh >> 4, h = bh & 15;

  const float lam = 1.f / (1.f + exp2f(-lamin[h] * LOG2E));
  const u16* kbase = K + ((size_t)(b * 2048)) * 2048 + h * 128;  // + s*2048 + c
  const u16* vbase = VT + ((size_t)(b * 16 + h) << 18);          // + d*2048 + s
  const f32x4 fzero = {0.f, 0.f, 0.f, 0.f};

  for (int phase = 0; phase < 2; ++phase) {
    const int it = phase ? 31 - pair : pair;
    const int t0 = it * 64;

    // Q fragments: kk=0,1 -> first 64 dims (S1), kk=2,3 -> second 64 (S2)
    bf16x8 qf[4];
    {
      const u16* qp = Q + (size_t)(b * 2048 + t0 + w * 16 + li) * 2048 + h * 128 + lh * 8;
#pragma unroll
      for (int kk = 0; kk < 4; ++kk) qf[kk] = *(const bf16x8*)(qp + kk * 32);
    }

    f32x4 o1[8], o2[8];
#pragma unroll
    for (int i = 0; i < 8; ++i) { o1[i] = fzero; o2[i] = fzero; }
    float l1p[4] = {0.f, 0.f, 0.f, 0.f};
    float l2p[4] = {0.f, 0.f, 0.f, 0.f};

    if (phase) __syncthreads();   // all waves done reading phase-0 buffers
    stage_kv(kbase, vbase, 0, Ks[0], Vs[0], w, lane);

    for (int j = 0; j <= it; ++j) {
      const int cur = j & 1;
      __syncthreads();  // DMA(j)->buf[cur] drained (vmcnt0); prior reads done
      if (j < it)       // prefetch j+1 into alt buffer; drains at NEXT barrier
        stage_kv(kbase, vbase, j + 1, Ks[cur ^ 1], Vs[cur ^ 1], w, lane);

      const u16* __restrict__ ks = Ks[cur];
      const u16* __restrict__ vs = Vs[cur];
      const bool diag = (j == it);

      // ---- per nt: S = Q@K^T chunk, exp, store P to LDS (wave-private) ----
#pragma unroll
      for (int nt = 0; nt < 4; ++nt) {
        const int srow = nt * 16 + li;
        const int sw = li & 7;
        bf16x8 b0 = *(const bf16x8*)&ks[srow * 128 + ((0 + lh) ^ sw) * 8];
        bf16x8 b1 = *(const bf16x8*)&ks[srow * 128 + ((4 + lh) ^ sw) * 8];
        bf16x8 b2 = *(const bf16x8*)&ks[srow * 128 + ((8 + lh) ^ sw) * 8];
        bf16x8 b3 = *(const bf16x8*)&ks[srow * 128 + ((12 + lh) ^ sw) * 8];
        f32x4 s1 = fzero, s2 = fzero;
        s1 = __builtin_amdgcn_mfma_f32_16x16x32_bf16(qf[0], b0, s1, 0, 0, 0);
        s1 = __builtin_amdgcn_mfma_f32_16x16x32_bf16(qf[1], b1, s1, 0, 0, 0);
        s2 = __builtin_amdgcn_mfma_f32_16x16x32_bf16(qf[2], b2, s2, 0, 0, 0);
        s2 = __builtin_amdgcn_mfma_f32_16x16x32_bf16(qf[3], b3, s2, 0, 0, 0);

        const int cb = nt * 2 + (li >> 3);
        const int sg = j * 64 + nt * 16 + li;
#pragma unroll
        for (int r = 0; r < 4; ++r) {
          const int row = w * 16 + lh * 4 + r;
          float p1, p2;
          if (diag && sg > t0 + row) {
            p1 = 0.f; p2 = 0.f;
          } else {
            p1 = exp2f(fmaf(s1[r], KS, -CB));
            p2 = exp2f(fmaf(s2[r], KS, -CB));
          }
          l1p[r] += p1; l2p[r] += p2;
          const int idx = row * 64 + ((cb ^ (row & 7)) << 3) + (li & 7);
          Ps1[idx] = f2bu(p1);
          Ps2[idx] = f2bu(p2);
        }
      }

      // ---- O += P @ V (A-frags from wave-private LDS rows; V from LDS) ----
#pragma unroll
      for (int kss = 0; kss < 2; ++kss) {
        const int arow = w * 16 + li;
        const int jb = ((kss * 4 + lh) ^ (li & 7)) * 8;
        bf16x8 a1f = *(const bf16x8*)&Ps1[arow * 64 + jb];
        bf16x8 a2f = *(const bf16x8*)&Ps2[arow * 64 + jb];
#pragma unroll
        for (int nt = 0; nt < 8; ++nt) {
          const int d = nt * 16 + li;
          bf16x8 vf = *(const bf16x8*)&vs[d * 64 + ((kss * 4 + lh) ^ (li & 7)) * 8];
          o1[nt] = __builtin_amdgcn_mfma_f32_16x16x32_bf16(a1f, vf, o1[nt], 0, 0, 0);
          o2[nt] = __builtin_amdgcn_mfma_f32_16x16x32_bf16(a2f, vf, o2[nt], 0, 0, 0);
        }
      }
    }

    // ---- one-shot l reduction across the 16 lanes holding each row --------
#pragma unroll
    for (int r = 0; r < 4; ++r) {
#pragma unroll
      for (int off = 1; off < 16; off <<= 1) {
        l1p[r] += __shfl_xor(l1p[r], off);
        l2p[r] += __shfl_xor(l2p[r], off);
      }
    }

    // ---- epilogue: O = O1/l1 - lam*O2/l2, bf16, layout (b, t, h*128+d) ----
#pragma unroll
    for (int r = 0; r < 4; ++r) {
      const float inv1 = 1.f / l1p[r];
      const float inv2 = lam / l2p[r];
      u16* orow = AO + (size_t)(b * 2048 + t0 + w * 16 + lh * 4 + r) * 2048 + h * 128 + li;
#pragma unroll
      for (int nt = 0; nt < 8; ++nt)
        orow[nt * 16] = f2bu(o1[nt][r] * inv1 - o2[nt][r] * inv2);
    }
  }
}

// ---------------------------------------------------------------------------
extern "C" void kernel_launch(void* const* d_in, const int* in_sizes, int n_in,
                              void* d_out, int out_size, void* d_ws, size_t ws_size,
                              hipStream_t stream) {
  const float* x   = (const float*)d_in[0];
  const float* Wq  = (const float*)d_in[1];
  const float* Wk  = (const float*)d_in[2];
  const float* Wv  = (const float*)d_in[3];
  const float* Wo  = (const float*)d_in[4];
  const float* lam = (const float*)d_in[5];
  float* out = (float*)d_out;

  const size_t MB = 1ull << 20;
  char* ws = (char*)d_ws;
  u16* qb = (u16*)d_out;            // 16 MB scratch inside d_out (rewritten at end)
  u16* kb = qb + (size_t)4096 * 2048;

  if (ws_size >= 56 * MB) {
    // ---- fused-QKV path ----
    u16* xb = (u16*)(ws);             // 16 MB: x bf16; later AO
    u16* wT = (u16*)(ws + 16 * MB);   // 24 MB: [WqT|WkT|WvT]; later WoT (8MB)
    u16* vt = (u16*)(ws + 40 * MB);   // 16 MB: V^T per head (b,h,d,t)
    u16* ao = xb;

    f32_to_bf16_k<<<8192, 256, 0, stream>>>(x, xb, 2097152);
    transpose_f32_bf16<<<dim3(64, 64), 256, 0, stream>>>(Wq, wT, 2048, 2048);
    transpose_f32_bf16<<<dim3(64, 64), 256, 0, stream>>>(Wk, wT + (size_t)4 * MB, 2048, 2048);
    transpose_f32_bf16<<<dim3(64, 64), 256, 0, stream>>>(Wv, wT + (size_t)8 * MB, 2048, 2048);
    // fused QKV, 256x256 m201-geometry tiles, 384 blocks
    gemm256_qkv<<<dim3(384), 512, 0, stream>>>(xb, wT, qb, vt, 2048);

    diff_attn<<<dim3(512), 256, 0, stream>>>(qb, kb, vt, lam, ao);

    transpose_f32_bf16<<<dim3(64, 64), 256, 0, stream>>>(Wo, wT, 2048, 2048);
    gemm_bt<1><<<dim3(32, 16), 256, 0, stream>>>(ao, wT, out, nullptr, 4096, 2048, 2048);
  } else {
    // ---- fallback: R5 sequence (40 MB scratch) ----
    u16* xb = (u16*)(ws);
    u16* wT = (u16*)(ws + 16 * MB);
    u16* vt = (u16*)(ws + 24 * MB);
    u16* ao = xb;

    f32_to_bf16_k<<<8192, 256, 0, stream>>>(x, xb, 2097152);
    transpose_f32_bf16<<<dim3(64, 64), 256, 0, stream>>>(Wq, wT, 2048, 2048);
    gemm_bt<0><<<dim3(32, 16), 256, 0, stream>>>(xb, wT, qb, nullptr, 4096, 2048, 2048);
    transpose_f32_bf16<<<dim3(64, 64), 256, 0, stream>>>(Wk, wT, 2048, 2048);
    gemm_bt<0><<<dim3(32, 16), 256, 0, stream>>>(xb, wT, kb, nullptr, 4096, 2048, 2048);
    transpose_f32_bf16<<<dim3(64, 64), 256, 0, stream>>>(Wv, wT, 2048, 2048);
    gemm_bt<2><<<dim3(32, 16), 256, 0, stream>>>(xb, wT, vt, nullptr, 4096, 2048, 2048);

    diff_attn<<<dim3(512), 256, 0, stream>>>(qb, kb, vt, lam, ao);

    transpose_f32_bf16<<<dim3(64, 64), 256, 0, stream>>>(Wo, wT, 2048, 2048);
    gemm_bt<1><<<dim3(32, 16), 256, 0, stream>>>(ao, wT, out, nullptr, 4096, 2048, 2048);
  }
}

// Round 7
// 399.054 us; speedup vs baseline: 1.0411x; 1.0411x over previous
//
#include <hip/hip_runtime.h>
#include <cstdint>
#include <cstddef>

// ---------------------------------------------------------------------------
// DifferentialAttention on MI355X (gfx950), bf16 MFMA pipeline.
// B=2 T=2048 D=2048 H=16 HD=128 HHD=64  SCALE=1/8
// R13: stop tunneling on QKV phases (R7-R12: per-phase 1650cy invariant to
//   everything tried). Whole-pipeline budget says out-proj (m97 128^2
//   structure, ~85us at N=2048 shape) is the next biggest lever.
//   - QKV: exact verified R11 kernel (130us), now gemm_pipe<0,3>.
//   - Out-proj: same verified template as gemm_pipe<1,1>: fp32 epilogue,
//     N=2048 -> 8 ntile cols, 1 col/XCD, grid 256 = exactly 1 round.
//   Only epilogue + grid mapping differ between instantiations.
// ---------------------------------------------------------------------------

typedef unsigned short u16;
typedef __bf16 bf16x8 __attribute__((ext_vector_type(8)));
typedef float f32x4 __attribute__((ext_vector_type(4)));

#define LOG2E 1.44269504088896340736f
// p = exp(s*0.125 - 8) = exp2(s * KS - CB); fixed bias 8 replaces running max
#define KS 0.18033688011112042f   /* 0.125 * log2(e) */
#define CB 11.541560327111707f    /* 8.0  * log2(e) */

__device__ __forceinline__ u16 f2bu(float f) {
  unsigned int x = __float_as_uint(f);
  x += 0x7fffu + ((x >> 16) & 1u);   // round-to-nearest-even (finite inputs)
  return (u16)(x >> 16);
}

// global -> LDS staging, 16B per lane. lds_uniform must be wave-uniform;
// hardware places lane's data at lds_uniform + lane*16.
__device__ __forceinline__ void stage16(const void* g, void* lds_uniform, int lane) {
#if defined(__has_builtin) && __has_builtin(__builtin_amdgcn_global_load_lds)
  (void)lane;
  __builtin_amdgcn_global_load_lds(
      (__attribute__((address_space(1))) void*)(g),
      (__attribute__((address_space(3))) void*)(lds_uniform), 16, 0, 0);
#else
  *(uint4*)((char*)lds_uniform + lane * 16) = *(const uint4*)g;
#endif
}

// two 16B/lane DMAs covering both k-slices of one 16KB half-tile:
// explicit +64B global / +8192B LDS between slices, offset imm always 0.
__device__ __forceinline__ void stage2(const char* g, void* lds_u) {
#if defined(__has_builtin) && __has_builtin(__builtin_amdgcn_global_load_lds)
  __builtin_amdgcn_global_load_lds(
      (__attribute__((address_space(1))) void*)g,
      (__attribute__((address_space(3))) void*)lds_u, 16, 0, 0);
  __builtin_amdgcn_global_load_lds(
      (__attribute__((address_space(1))) void*)(g + 64),
      (__attribute__((address_space(3))) void*)((char*)lds_u + 8192), 16, 0, 0);
#endif
}

// ---------------------------------------------------------------------------
// fp32 -> bf16 elementwise (vectorized), exact-grid
// ---------------------------------------------------------------------------
__global__ void f32_to_bf16_k(const float* __restrict__ in, u16* __restrict__ out, int n4) {
  int i = blockIdx.x * blockDim.x + threadIdx.x;
  if (i < n4) {
    float4 v = ((const float4*)in)[i];
    ushort4 u;
    u.x = f2bu(v.x); u.y = f2bu(v.y); u.z = f2bu(v.z); u.w = f2bu(v.w);
    ((ushort4*)out)[i] = u;
  }
}

// ---------------------------------------------------------------------------
// fp32 (R x C) -> bf16 transposed (C x R), 32x32 LDS tiles
// ---------------------------------------------------------------------------
__global__ void transpose_f32_bf16(const float* __restrict__ in, u16* __restrict__ out,
                                   int R, int C) {
  __shared__ u16 tile[32][33];
  const int tx = threadIdx.x & 31, ty = threadIdx.x >> 5; // 32 x 8
  const int c0 = blockIdx.x * 32, r0 = blockIdx.y * 32;
#pragma unroll
  for (int i = 0; i < 32; i += 8)
    tile[ty + i][tx] = f2bu(in[(size_t)(r0 + ty + i) * C + c0 + tx]);
  __syncthreads();
#pragma unroll
  for (int i = 0; i < 32; i += 8)
    out[(size_t)(c0 + ty + i) * R + r0 + tx] = tile[tx][ty + i];
}

// ---------------------------------------------------------------------------
// Legacy 128x128 GEMM (m97-structure) — fallback path only.
// C(M,N) = A(M,K) @ BT(N,K)^T   all bf16 in, fp32 accumulate.
// MODE 0: bf16 natural   MODE 1: fp32 natural
// MODE 2: bf16 V-transpose -> out[((b*16+h)*128+d)*2048 + t]
// ---------------------------------------------------------------------------
template <int MODE>
__global__ void gemm_bt(const u16* __restrict__ A, const u16* __restrict__ BT,
                        void* __restrict__ C, u16* __restrict__ C2,
                        int Mdim, int Ndim, int Kdim) {
  __shared__ __align__(16) u16 As[128 * 32];
  __shared__ __align__(16) u16 Bs[128 * 32];
  const int tid = threadIdx.x;
  const int lane = tid & 63;
  const int w = tid >> 6;
  const int wm = w & 1, wn = w >> 1;
  const int li = lane & 15, lh = lane >> 4;
  const int m0 = blockIdx.x * 128;
  const int n0 = blockIdx.y * 128;

  const f32x4 fzero = {0.f, 0.f, 0.f, 0.f};
  f32x4 acc[4][4];
#pragma unroll
  for (int i = 0; i < 4; ++i)
#pragma unroll
    for (int jj = 0; jj < 4; ++jj) acc[i][jj] = fzero;

  for (int k0 = 0; k0 < Kdim; k0 += 32) {
#pragma unroll
    for (int i = 0; i < 2; ++i) {
      const int c = i * 256 + w * 64 + lane;
      stage16(A + (size_t)(m0 + (c >> 2)) * Kdim + k0 + ((c & 3) << 3),
              (char*)As + (size_t)(i * 256 + w * 64) * 16, lane);
      stage16(BT + (size_t)(n0 + (c >> 2)) * Kdim + k0 + ((c & 3) << 3),
              (char*)Bs + (size_t)(i * 256 + w * 64) * 16, lane);
    }
    __syncthreads();

    bf16x8 af[4], bfr[4];
#pragma unroll
    for (int mt = 0; mt < 4; ++mt)
      af[mt] = *(const bf16x8*)&As[(wm * 64 + mt * 16 + li) * 32 + lh * 8];
#pragma unroll
    for (int nt = 0; nt < 4; ++nt)
      bfr[nt] = *(const bf16x8*)&Bs[(wn * 64 + nt * 16 + li) * 32 + lh * 8];
#pragma unroll
    for (int mt = 0; mt < 4; ++mt)
#pragma unroll
      for (int nt = 0; nt < 4; ++nt)
        acc[mt][nt] = __builtin_amdgcn_mfma_f32_16x16x32_bf16(af[mt], bfr[nt], acc[mt][nt], 0, 0, 0);
    __syncthreads();
  }

  // epilogue: C/D layout col = lane&15, row = (lane>>4)*4 + reg
#pragma unroll
  for (int mt = 0; mt < 4; ++mt) {
#pragma unroll
    for (int nt = 0; nt < 4; ++nt) {
      const int mb = m0 + wm * 64 + mt * 16 + lh * 4; // 4 consecutive rows
      const int n = n0 + wn * 64 + nt * 16 + li;
      if (MODE == 0) {
        u16* o = (u16*)C;
#pragma unroll
        for (int r = 0; r < 4; ++r)
          o[(size_t)(mb + r) * Ndim + n] = f2bu(acc[mt][nt][r]);
      } else if (MODE == 1) {
        float* o = (float*)C;
#pragma unroll
        for (int r = 0; r < 4; ++r)
          o[(size_t)(mb + r) * Ndim + n] = acc[mt][nt][r];
      } else {
        u16* o = (u16*)C;
        const int bb = mb >> 11, t = mb & 2047;
        const int hh = n >> 7, d = n & 127;
        ushort4 u;
        u.x = f2bu(acc[mt][nt][0]);
        u.y = f2bu(acc[mt][nt][1]);
        u.z = f2bu(acc[mt][nt][2]);
        u.w = f2bu(acc[mt][nt][3]);
        *(ushort4*)&o[((size_t)((bb * 16 + hh) * 128 + d) << 11) + t] = u;
      }
    }
  }
}

// ---------------------------------------------------------------------------
// 128x256 2-phase-per-K-tile pipelined GEMM (verified R11 structure),
// templated on epilogue / grid mapping.
//   OMODE 0: fused QKV. N=6144, NTPX=3 (xcd owns ntiles [3x,3x+2]), grid 768
//            = 3 exact rounds. n<2048->Q into C; n<4096->K into C+4096*2048;
//            else V per-head transposed into C2.
//   OMODE 1: out-projection. N=2048, NTPX=1 (xcd owns 1 ntile col), grid 256
//            = 1 exact round. fp32 direct store into C.
// K hardcoded 2048 (NT=32). LDS slots 16KB [2 ks][128 rows][32 elem],
// st_16x32 swizzle on the pre-swizzled global source; reads XOR via lhx8.
//   A ring: 3 full-tile slots, read slot kt%3, stage A(kt+2)->(kt+2)%3.
//   B ring: 6 half-tile slots, read slot (2kt+wh)%6, stage B(2kt+3) [P0],
//           B(2kt+4) [P1]; P1 tail vmcnt(2) (vmcnt(0) for last two tiles).
// Race distances all >= one closing barrier (proofs in R9/R11 notes).
// ---------------------------------------------------------------------------
template <int OMODE, int NTPX>
__global__ __launch_bounds__(512, 2)
void gemm_pipe(const u16* __restrict__ A, const u16* __restrict__ BT,
               void* __restrict__ C, u16* __restrict__ C2) {
  __shared__ __align__(16) u16 As[3][2][128][32];   // 48KB, A full-tile ring
  __shared__ __align__(16) u16 Bs[6][2][128][32];   // 96KB, B half-tile ring

  const int tid = threadIdx.x;
  const int w = tid >> 6;              // 0..7
  const int lane = tid & 63;
  const int wm = w >> 2;               // M-half of the 128-row tile (64 rows)
  const int wn = w & 3;                // N quarter (64 cols)
  const int wh = wn >> 1;              // which B half-tile this wave reads
  const int li = lane & 15, lh = lane >> 4;
  const int lhx8 = (lh ^ (((li >> 3) & 1) << 1)) * 8;   // swizzled k-chunk
  const int brow = (wn & 1) * 64;      // row base inside B half-tile

  // XCD-aware swizzle: xcd owns NTPX consecutive ntile columns.
  const int bid = blockIdx.x;
  const int xcd = bid & 7;
  const int local = bid >> 3;
  const int mtile = local / NTPX;
  const int ntile = xcd * NTPX + (local % NTPX);
  const int m0 = mtile * 128, n0 = ntile * 256;

  // per-lane staging source offset (st_16x32 pre-swizzle), constant per lane
  const int o = tid << 4;                          // byte in 8KB k-slice image
  const int osz = o ^ (((o >> 9) & 1) << 5);       // involution
  const int srow = osz >> 6;                       // 0..127
  const int skel = (osz & 63) >> 1;                // element in 32-slice
  const size_t soff = ((size_t)srow * 2048 + skel) * 2;  // bytes

  const char* pA  = (const char*)A  + (size_t)m0 * 4096 + soff;  // next A tile
  const char* pB0 = (const char*)BT + (size_t)n0 * 4096 + soff;  // even halves
  const char* pB1 = pB0 + (size_t)128 * 4096;                    // odd halves

#define STAGE_A(SLOT)    { stage2(pA,  (char*)As + (SLOT) * 16384 + w * 1024); pA  += 128; }
#define STAGE_BODD(SLOT) { stage2(pB1, (char*)Bs + (SLOT) * 16384 + w * 1024); pB1 += 128; }
#define STAGE_BEVEN(SLOT){ stage2(pB0, (char*)Bs + (SLOT) * 16384 + w * 1024); pB0 += 128; }

  const f32x4 fzero = {0.f, 0.f, 0.f, 0.f};
  f32x4 acc[4][4];
#pragma unroll
  for (int i = 0; i < 4; ++i)
#pragma unroll
    for (int jj = 0; jj < 4; ++jj) acc[i][jj] = fzero;

  // prologue: A0,B0,B1,A1,B2 (10 instrs); vmcnt(3) confirms tile 0's operands
  STAGE_A(0); STAGE_BEVEN(0); STAGE_BODD(1); STAGE_A(1); STAGE_BEVEN(2);
  asm volatile("s_waitcnt vmcnt(3)" ::: "memory");
  __builtin_amdgcn_s_barrier();
  asm volatile("" ::: "memory");

#define QPHASE(SA, SB2, KSI, STAGES, TAIL)                                     \
  {                                                                            \
    bf16x8 af[4], bfc[4];                                                      \
    _Pragma("unroll")                                                          \
    for (int mq = 0; mq < 4; ++mq)                                             \
      af[mq] = *(const bf16x8*)&As[(SA)][(KSI)][wm * 64 + mq * 16 + li][lhx8]; \
    _Pragma("unroll")                                                          \
    for (int nt = 0; nt < 4; ++nt)                                             \
      bfc[nt] = *(const bf16x8*)&Bs[(SB2) + wh][(KSI)][brow + nt * 16 + li][lhx8]; \
    STAGES;                                                                    \
    __builtin_amdgcn_s_barrier();                                              \
    asm volatile("" ::: "memory");                                             \
    __builtin_amdgcn_s_setprio(1);                                             \
    _Pragma("unroll")                                                          \
    for (int mq = 0; mq < 4; ++mq) {                                           \
      _Pragma("unroll")                                                        \
      for (int nt = 0; nt < 4; ++nt)                                           \
        acc[mq][nt] = __builtin_amdgcn_mfma_f32_16x16x32_bf16(                 \
            af[mq], bfc[nt], acc[mq][nt], 0, 0, 0);                            \
    }                                                                          \
    __builtin_amdgcn_s_setprio(0);                                             \
    TAIL;                                                                      \
    __builtin_amdgcn_s_barrier();                                              \
    asm volatile("" ::: "memory");                                             \
  }

#define TILE_MAIN(U)                                                           \
  QPHASE((U), 2 * (U), 0,                                                      \
         { STAGE_A(((U) + 2) % 3); STAGE_BODD((2 * (U) + 3) % 6); }, ((void)0)) \
  QPHASE((U), 2 * (U), 1, { STAGE_BEVEN((2 * (U) + 4) % 6); },                 \
         asm volatile("s_waitcnt vmcnt(2)" ::: "memory"))

  for (int t3 = 0; t3 < 10; ++t3) {   // tiles 0..29, slots period-3 in kt
    TILE_MAIN(0)
    TILE_MAIN(1)
    TILE_MAIN(2)
  }
  // kt=30: A slot 0, B base slot 0; stage B(63)->slot 3; drain at P1.
  QPHASE(0, 0, 0, { STAGE_BODD(3); }, ((void)0))
  QPHASE(0, 0, 1, ((void)0), asm volatile("s_waitcnt vmcnt(0)" ::: "memory"))
  // kt=31: A slot 1, B base slot 2; nothing in flight.
  QPHASE(1, 2, 0, ((void)0), ((void)0))
  QPHASE(1, 2, 1, ((void)0), ((void)0))

#undef QPHASE
#undef TILE_MAIN
#undef STAGE_A
#undef STAGE_BODD
#undef STAGE_BEVEN

  // epilogue: C/D layout col = lane&15, row = (lane>>4)*4 + reg
  const int nB0 = (OMODE == 0 ? (n0 & 2047) : n0) + wn * 64;
  const int mB = m0 + wm * 64;
  const int proj = n0 >> 11;                 // OMODE 0: 0=Q,1=K,2=V
#pragma unroll
  for (int mt = 0; mt < 4; ++mt) {
#pragma unroll
    for (int nt = 0; nt < 4; ++nt) {
      const int mb = mB + mt * 16 + lh * 4;  // 4 consecutive rows
      const int n = nB0 + nt * 16 + li;
      if (OMODE == 1) {
        float* o = (float*)C;
#pragma unroll
        for (int r = 0; r < 4; ++r)
          o[(size_t)(mb + r) * 2048 + n] = acc[mt][nt][r];
      } else if (proj < 2) {
        u16* o = (u16*)C + (size_t)proj * 4096 * 2048;
#pragma unroll
        for (int r = 0; r < 4; ++r)
          o[(size_t)(mb + r) * 2048 + n] = f2bu(acc[mt][nt][r]);
      } else {
        const int bb = mb >> 11, t = mb & 2047;
        const int hh = n >> 7, d = n & 127;
        ushort4 u;
        u.x = f2bu(acc[mt][nt][0]);
        u.y = f2bu(acc[mt][nt][1]);
        u.z = f2bu(acc[mt][nt][2]);
        u.w = f2bu(acc[mt][nt][3]);
        *(ushort4*)&C2[((size_t)((bb * 16 + hh) * 128 + d) << 11) + t] = u;
      }
    }
  }
}

// ---------------------------------------------------------------------------
// Flash differential attention: paired q-tiles, double-buffered DMA.
// grid = 512 (1D): bh = idx&31 (XCD pin), pair = idx>>5 in [0,16).
// Block processes q-tile `pair` then q-tile `31-pair` -> 33 iters uniform.
// Per iter: one barrier; prefetch K/V(j+1) into alt buffer right after it.
// Wave w owns Q rows t0+w*16..+15; P round-trip is wave-private (no barrier).
// Fixed-bias softmax; l reduced once per phase. LDS 80KB -> 2 blocks/CU.
// ---------------------------------------------------------------------------
__device__ __forceinline__ void stage_kv(const u16* __restrict__ kbase,
                                         const u16* __restrict__ vbase, int j,
                                         u16* ksBuf, u16* vsBuf, int w, int lane) {
  const int kst_r = lane >> 4, kst_c = lane & 15;
  const int vst_r = lane >> 3, vst_c = lane & 7;
#pragma unroll
  for (int i = 0; i < 4; ++i) {
    const int t = w * 4 + i;
    const int srow = t * 4 + kst_r;
    const int scb = kst_c ^ (srow & 7);
    stage16(kbase + (size_t)(j * 64 + srow) * 2048 + scb * 8,
            (char*)ksBuf + t * 1024, lane);
    const int drow = t * 8 + vst_r;
    const int dcb = vst_c ^ (drow & 7);
    stage16(vbase + (size_t)drow * 2048 + j * 64 + dcb * 8,
            (char*)vsBuf + t * 1024, lane);
  }
}

__global__ __launch_bounds__(256, 2)
void diff_attn(const u16* __restrict__ Q, const u16* __restrict__ K,
               const u16* __restrict__ VT, const float* __restrict__ lamin,
               u16* __restrict__ AO) {
  __shared__ __align__(16) u16 Ks[2][64 * 128];   // [s][c], col-block swizzled
  __shared__ __align__(16) u16 Vs[2][128 * 64];   // [d][s], col-block swizzled
  __shared__ __align__(16) u16 Ps1[64 * 64];
  __shared__ __align__(16) u16 Ps2[64 * 64];

  const int tid = threadIdx.x, lane = tid & 63, w = tid >> 6;
  const int li = lane & 15, lh = lane >> 4;
  const int bh = blockIdx.x & 31, pair = blockIdx.x >> 5;
  const int b = bh >> 4, h = bh & 15;

  const float lam = 1.f / (1.f + exp2f(-lamin[h] * LOG2E));
  const u16* kbase = K + ((size_t)(b * 2048)) * 2048 + h * 128;  // + s*2048 + c
  const u16* vbase = VT + ((size_t)(b * 16 + h) << 18);          // + d*2048 + s
  const f32x4 fzero = {0.f, 0.f, 0.f, 0.f};

  for (int phase = 0; phase < 2; ++phase) {
    const int it = phase ? 31 - pair : pair;
    const int t0 = it * 64;

    // Q fragments: kk=0,1 -> first 64 dims (S1), kk=2,3 -> second 64 (S2)
    bf16x8 qf[4];
    {
      const u16* qp = Q + (size_t)(b * 2048 + t0 + w * 16 + li) * 2048 + h * 128 + lh * 8;
#pragma unroll
      for (int kk = 0; kk < 4; ++kk) qf[kk] = *(const bf16x8*)(qp + kk * 32);
    }

    f32x4 o1[8], o2[8];
#pragma unroll
    for (int i = 0; i < 8; ++i) { o1[i] = fzero; o2[i] = fzero; }
    float l1p[4] = {0.f, 0.f, 0.f, 0.f};
    float l2p[4] = {0.f, 0.f, 0.f, 0.f};

    if (phase) __syncthreads();   // all waves done reading phase-0 buffers
    stage_kv(kbase, vbase, 0, Ks[0], Vs[0], w, lane);

    for (int j = 0; j <= it; ++j) {
      const int cur = j & 1;
      __syncthreads();  // DMA(j)->buf[cur] drained (vmcnt0); prior reads done
      if (j < it)       // prefetch j+1 into alt buffer; drains at NEXT barrier
        stage_kv(kbase, vbase, j + 1, Ks[cur ^ 1], Vs[cur ^ 1], w, lane);

      const u16* __restrict__ ks = Ks[cur];
      const u16* __restrict__ vs = Vs[cur];
      const bool diag = (j == it);

      // ---- per nt: S = Q@K^T chunk, exp, store P to LDS (wave-private) ----
#pragma unroll
      for (int nt = 0; nt < 4; ++nt) {
        const int srow = nt * 16 + li;
        const int sw = li & 7;
        bf16x8 b0 = *(const bf16x8*)&ks[srow * 128 + ((0 + lh) ^ sw) * 8];
        bf16x8 b1 = *(const bf16x8*)&ks[srow * 128 + ((4 + lh) ^ sw) * 8];
        bf16x8 b2 = *(const bf16x8*)&ks[srow * 128 + ((8 + lh) ^ sw) * 8];
        bf16x8 b3 = *(const bf16x8*)&ks[srow * 128 + ((12 + lh) ^ sw) * 8];
        f32x4 s1 = fzero, s2 = fzero;
        s1 = __builtin_amdgcn_mfma_f32_16x16x32_bf16(qf[0], b0, s1, 0, 0, 0);
        s1 = __builtin_amdgcn_mfma_f32_16x16x32_bf16(qf[1], b1, s1, 0, 0, 0);
        s2 = __builtin_amdgcn_mfma_f32_16x16x32_bf16(qf[2], b2, s2, 0, 0, 0);
        s2 = __builtin_amdgcn_mfma_f32_16x16x32_bf16(qf[3], b3, s2, 0, 0, 0);

        const int cb = nt * 2 + (li >> 3);
        const int sg = j * 64 + nt * 16 + li;
#pragma unroll
        for (int r = 0; r < 4; ++r) {
          const int row = w * 16 + lh * 4 + r;
          float p1, p2;
          if (diag && sg > t0 + row) {
            p1 = 0.f; p2 = 0.f;
          } else {
            p1 = exp2f(fmaf(s1[r], KS, -CB));
            p2 = exp2f(fmaf(s2[r], KS, -CB));
          }
          l1p[r] += p1; l2p[r] += p2;
          const int idx = row * 64 + ((cb ^ (row & 7)) << 3) + (li & 7);
          Ps1[idx] = f2bu(p1);
          Ps2[idx] = f2bu(p2);
        }
      }

      // ---- O += P @ V (A-frags from wave-private LDS rows; V from LDS) ----
#pragma unroll
      for (int kss = 0; kss < 2; ++kss) {
        const int arow = w * 16 + li;
        const int jb = ((kss * 4 + lh) ^ (li & 7)) * 8;
        bf16x8 a1f = *(const bf16x8*)&Ps1[arow * 64 + jb];
        bf16x8 a2f = *(const bf16x8*)&Ps2[arow * 64 + jb];
#pragma unroll
        for (int nt = 0; nt < 8; ++nt) {
          const int d = nt * 16 + li;
          bf16x8 vf = *(const bf16x8*)&vs[d * 64 + ((kss * 4 + lh) ^ (li & 7)) * 8];
          o1[nt] = __builtin_amdgcn_mfma_f32_16x16x32_bf16(a1f, vf, o1[nt], 0, 0, 0);
          o2[nt] = __builtin_amdgcn_mfma_f32_16x16x32_bf16(a2f, vf, o2[nt], 0, 0, 0);
        }
      }
    }

    // ---- one-shot l reduction across the 16 lanes holding each row --------
#pragma unroll
    for (int r = 0; r < 4; ++r) {
#pragma unroll
      for (int off = 1; off < 16; off <<= 1) {
        l1p[r] += __shfl_xor(l1p[r], off);
        l2p[r] += __shfl_xor(l2p[r], off);
      }
    }

    // ---- epilogue: O = O1/l1 - lam*O2/l2, bf16, layout (b, t, h*128+d) ----
#pragma unroll
    for (int r = 0; r < 4; ++r) {
      const float inv1 = 1.f / l1p[r];
      const float inv2 = lam / l2p[r];
      u16* orow = AO + (size_t)(b * 2048 + t0 + w * 16 + lh * 4 + r) * 2048 + h * 128 + li;
#pragma unroll
      for (int nt = 0; nt < 8; ++nt)
        orow[nt * 16] = f2bu(o1[nt][r] * inv1 - o2[nt][r] * inv2);
    }
  }
}

// ---------------------------------------------------------------------------
extern "C" void kernel_launch(void* const* d_in, const int* in_sizes, int n_in,
                              void* d_out, int out_size, void* d_ws, size_t ws_size,
                              hipStream_t stream) {
  const float* x   = (const float*)d_in[0];
  const float* Wq  = (const float*)d_in[1];
  const float* Wk  = (const float*)d_in[2];
  const float* Wv  = (const float*)d_in[3];
  const float* Wo  = (const float*)d_in[4];
  const float* lam = (const float*)d_in[5];
  float* out = (float*)d_out;

  const size_t MB = 1ull << 20;
  char* ws = (char*)d_ws;
  u16* qb = (u16*)d_out;            // 16 MB scratch inside d_out (rewritten at end)
  u16* kb = qb + (size_t)4096 * 2048;

  if (ws_size >= 56 * MB) {
    // ---- fused-QKV path ----
    u16* xb = (u16*)(ws);             // 16 MB: x bf16; later AO
    u16* wT = (u16*)(ws + 16 * MB);   // 24 MB: [WqT|WkT|WvT]; later WoT (8MB)
    u16* vt = (u16*)(ws + 40 * MB);   // 16 MB: V^T per head (b,h,d,t)
    u16* ao = xb;

    f32_to_bf16_k<<<8192, 256, 0, stream>>>(x, xb, 2097152);
    transpose_f32_bf16<<<dim3(64, 64), 256, 0, stream>>>(Wq, wT, 2048, 2048);
    transpose_f32_bf16<<<dim3(64, 64), 256, 0, stream>>>(Wk, wT + (size_t)4 * MB, 2048, 2048);
    transpose_f32_bf16<<<dim3(64, 64), 256, 0, stream>>>(Wv, wT + (size_t)8 * MB, 2048, 2048);
    // fused QKV, 128x256 tiles, 768 blocks = 3 exact rounds
    gemm_pipe<0, 3><<<dim3(768), 512, 0, stream>>>(xb, wT, qb, vt);

    diff_attn<<<dim3(512), 256, 0, stream>>>(qb, kb, vt, lam, ao);

    transpose_f32_bf16<<<dim3(64, 64), 256, 0, stream>>>(Wo, wT, 2048, 2048);
    // out-projection on the same pipelined template: 256 blocks = 1 round
    gemm_pipe<1, 1><<<dim3(256), 512, 0, stream>>>(ao, wT, out, nullptr);
  } else {
    // ---- fallback: R5 sequence (40 MB scratch) ----
    u16* xb = (u16*)(ws);
    u16* wT = (u16*)(ws + 16 * MB);
    u16* vt = (u16*)(ws + 24 * MB);
    u16* ao = xb;

    f32_to_bf16_k<<<8192, 256, 0, stream>>>(x, xb, 2097152);
    transpose_f32_bf16<<<dim3(64, 64), 256, 0, stream>>>(Wq, wT, 2048, 2048);
    gemm_bt<0><<<dim3(32, 16), 256, 0, stream>>>(xb, wT, qb, nullptr, 4096, 2048, 2048);
    transpose_f32_bf16<<<dim3(64, 64), 256, 0, stream>>>(Wk, wT, 2048, 2048);
    gemm_bt<0><<<dim3(32, 16), 256, 0, stream>>>(xb, wT, kb, nullptr, 4096, 2048, 2048);
    transpose_f32_bf16<<<dim3(64, 64), 256, 0, stream>>>(Wv, wT, 2048, 2048);
    gemm_bt<2><<<dim3(32, 16), 256, 0, stream>>>(xb, wT, vt, nullptr, 4096, 2048, 2048);

    diff_attn<<<dim3(512), 256, 0, stream>>>(qb, kb, vt, lam, ao);

    transpose_f32_bf16<<<dim3(64, 64), 256, 0, stream>>>(Wo, wT, 2048, 2048);
    gemm_bt<1><<<dim3(32, 16), 256, 0, stream>>>(ao, wT, out, nullptr, 4096, 2048, 2048);
  }
}

// Round 8
// 390.096 us; speedup vs baseline: 1.0650x; 1.0230x over previous
//
#include <hip/hip_runtime.h>
#include <cstdint>
#include <cstddef>

// ---------------------------------------------------------------------------
// DifferentialAttention on MI355X (gfx950), bf16 MFMA pipeline.
// B=2 T=2048 D=2048 H=16 HD=128 HHD=64  SCALE=1/8
// R14: occupancy attack on the QKV GEMM. R7-R13 invariant: ~1670cy/phase at
//   1 block/CU (144KB LDS, 2 waves/SIMD lockstep) regardless of schedule.
//   gemm_qkv2: SAME per-phase content (16 MFMA + 8 b128 reads/wave) but
//   72KB LDS -> 2 blocks/CU: BK=32, 1 phase/K-step, A ring 3x8KB [128][32],
//   B ring 3x16KB [256][32], stage j+2 (3 instr/wave/phase), vmcnt(3) tail.
//   Co-resident block absorbs barrier/latency stalls; LDS pipe becomes the
//   shared saturated resource (~800cy/block-phase predicted).
//   Out-proj stays on verified gemm_pipe<1,1>. Wq/Wk/Wv transposes merged
//   into one launch. All stager/swizzle math byte-reused from R11/R12.
// ---------------------------------------------------------------------------

typedef unsigned short u16;
typedef __bf16 bf16x8 __attribute__((ext_vector_type(8)));
typedef float f32x4 __attribute__((ext_vector_type(4)));

#define LOG2E 1.44269504088896340736f
// p = exp(s*0.125 - 8) = exp2(s * KS - CB); fixed bias 8 replaces running max
#define KS 0.18033688011112042f   /* 0.125 * log2(e) */
#define CB 11.541560327111707f    /* 8.0  * log2(e) */

__device__ __forceinline__ u16 f2bu(float f) {
  unsigned int x = __float_as_uint(f);
  x += 0x7fffu + ((x >> 16) & 1u);   // round-to-nearest-even (finite inputs)
  return (u16)(x >> 16);
}

// global -> LDS staging, 16B per lane. lds_uniform must be wave-uniform;
// hardware places lane's data at lds_uniform + lane*16.
__device__ __forceinline__ void stage16(const void* g, void* lds_uniform, int lane) {
#if defined(__has_builtin) && __has_builtin(__builtin_amdgcn_global_load_lds)
  (void)lane;
  __builtin_amdgcn_global_load_lds(
      (__attribute__((address_space(1))) void*)(g),
      (__attribute__((address_space(3))) void*)(lds_uniform), 16, 0, 0);
#else
  *(uint4*)((char*)lds_uniform + lane * 16) = *(const uint4*)g;
#endif
}

// two 16B/lane DMAs: rows [0,128) and [128,256) of a 16KB [256][32] slot.
// Explicit +128*4096B global / +8192B LDS, offset imm always 0. (R12-verified)
__device__ __forceinline__ void stageK(const char* g, char* lds_u) {
#if defined(__has_builtin) && __has_builtin(__builtin_amdgcn_global_load_lds)
  __builtin_amdgcn_global_load_lds(
      (__attribute__((address_space(1))) void*)g,
      (__attribute__((address_space(3))) void*)lds_u, 16, 0, 0);
  __builtin_amdgcn_global_load_lds(
      (__attribute__((address_space(1))) void*)(g + (size_t)128 * 4096),
      (__attribute__((address_space(3))) void*)(lds_u + 8192), 16, 0, 0);
#endif
}

// two 16B/lane DMAs covering both k-slices of one 16KB half-tile (R11 path).
__device__ __forceinline__ void stage2(const char* g, void* lds_u) {
#if defined(__has_builtin) && __has_builtin(__builtin_amdgcn_global_load_lds)
  __builtin_amdgcn_global_load_lds(
      (__attribute__((address_space(1))) void*)g,
      (__attribute__((address_space(3))) void*)lds_u, 16, 0, 0);
  __builtin_amdgcn_global_load_lds(
      (__attribute__((address_space(1))) void*)(g + 64),
      (__attribute__((address_space(3))) void*)((char*)lds_u + 8192), 16, 0, 0);
#endif
}

// ---------------------------------------------------------------------------
// fp32 -> bf16 elementwise (vectorized), exact-grid
// ---------------------------------------------------------------------------
__global__ void f32_to_bf16_k(const float* __restrict__ in, u16* __restrict__ out, int n4) {
  int i = blockIdx.x * blockDim.x + threadIdx.x;
  if (i < n4) {
    float4 v = ((const float4*)in)[i];
    ushort4 u;
    u.x = f2bu(v.x); u.y = f2bu(v.y); u.z = f2bu(v.z); u.w = f2bu(v.w);
    ((ushort4*)out)[i] = u;
  }
}

// ---------------------------------------------------------------------------
// fp32 (R x C) -> bf16 transposed (C x R), 32x32 LDS tiles
// ---------------------------------------------------------------------------
__global__ void transpose_f32_bf16(const float* __restrict__ in, u16* __restrict__ out,
                                   int R, int C) {
  __shared__ u16 tile[32][33];
  const int tx = threadIdx.x & 31, ty = threadIdx.x >> 5; // 32 x 8
  const int c0 = blockIdx.x * 32, r0 = blockIdx.y * 32;
#pragma unroll
  for (int i = 0; i < 32; i += 8)
    tile[ty + i][tx] = f2bu(in[(size_t)(r0 + ty + i) * C + c0 + tx]);
  __syncthreads();
#pragma unroll
  for (int i = 0; i < 32; i += 8)
    out[(size_t)(c0 + ty + i) * R + r0 + tx] = tile[tx][ty + i];
}

// three 2048x2048 transposes in one launch (blockIdx.z selects weight)
__global__ void transpose3_f32_bf16(const float* __restrict__ W0,
                                    const float* __restrict__ W1,
                                    const float* __restrict__ W2,
                                    u16* __restrict__ out) {
  __shared__ u16 tile[32][33];
  const float* in = blockIdx.z == 0 ? W0 : (blockIdx.z == 1 ? W1 : W2);
  u16* o = out + (size_t)blockIdx.z * 2048 * 2048;
  const int tx = threadIdx.x & 31, ty = threadIdx.x >> 5; // 32 x 8
  const int c0 = blockIdx.x * 32, r0 = blockIdx.y * 32;
#pragma unroll
  for (int i = 0; i < 32; i += 8)
    tile[ty + i][tx] = f2bu(in[(size_t)(r0 + ty + i) * 2048 + c0 + tx]);
  __syncthreads();
#pragma unroll
  for (int i = 0; i < 32; i += 8)
    o[(size_t)(c0 + ty + i) * 2048 + r0 + tx] = tile[tx][ty + i];
}

// ---------------------------------------------------------------------------
// Legacy 128x128 GEMM (m97-structure) — fallback path only.
// ---------------------------------------------------------------------------
template <int MODE>
__global__ void gemm_bt(const u16* __restrict__ A, const u16* __restrict__ BT,
                        void* __restrict__ C, u16* __restrict__ C2,
                        int Mdim, int Ndim, int Kdim) {
  __shared__ __align__(16) u16 As[128 * 32];
  __shared__ __align__(16) u16 Bs[128 * 32];
  const int tid = threadIdx.x;
  const int lane = tid & 63;
  const int w = tid >> 6;
  const int wm = w & 1, wn = w >> 1;
  const int li = lane & 15, lh = lane >> 4;
  const int m0 = blockIdx.x * 128;
  const int n0 = blockIdx.y * 128;

  const f32x4 fzero = {0.f, 0.f, 0.f, 0.f};
  f32x4 acc[4][4];
#pragma unroll
  for (int i = 0; i < 4; ++i)
#pragma unroll
    for (int jj = 0; jj < 4; ++jj) acc[i][jj] = fzero;

  for (int k0 = 0; k0 < Kdim; k0 += 32) {
#pragma unroll
    for (int i = 0; i < 2; ++i) {
      const int c = i * 256 + w * 64 + lane;
      stage16(A + (size_t)(m0 + (c >> 2)) * Kdim + k0 + ((c & 3) << 3),
              (char*)As + (size_t)(i * 256 + w * 64) * 16, lane);
      stage16(BT + (size_t)(n0 + (c >> 2)) * Kdim + k0 + ((c & 3) << 3),
              (char*)Bs + (size_t)(i * 256 + w * 64) * 16, lane);
    }
    __syncthreads();

    bf16x8 af[4], bfr[4];
#pragma unroll
    for (int mt = 0; mt < 4; ++mt)
      af[mt] = *(const bf16x8*)&As[(wm * 64 + mt * 16 + li) * 32 + lh * 8];
#pragma unroll
    for (int nt = 0; nt < 4; ++nt)
      bfr[nt] = *(const bf16x8*)&Bs[(wn * 64 + nt * 16 + li) * 32 + lh * 8];
#pragma unroll
    for (int mt = 0; mt < 4; ++mt)
#pragma unroll
      for (int nt = 0; nt < 4; ++nt)
        acc[mt][nt] = __builtin_amdgcn_mfma_f32_16x16x32_bf16(af[mt], bfr[nt], acc[mt][nt], 0, 0, 0);
    __syncthreads();
  }

#pragma unroll
  for (int mt = 0; mt < 4; ++mt) {
#pragma unroll
    for (int nt = 0; nt < 4; ++nt) {
      const int mb = m0 + wm * 64 + mt * 16 + lh * 4;
      const int n = n0 + wn * 64 + nt * 16 + li;
      if (MODE == 0) {
        u16* o = (u16*)C;
#pragma unroll
        for (int r = 0; r < 4; ++r)
          o[(size_t)(mb + r) * Ndim + n] = f2bu(acc[mt][nt][r]);
      } else if (MODE == 1) {
        float* o = (float*)C;
#pragma unroll
        for (int r = 0; r < 4; ++r)
          o[(size_t)(mb + r) * Ndim + n] = acc[mt][nt][r];
      } else {
        u16* o = (u16*)C;
        const int bb = mb >> 11, t = mb & 2047;
        const int hh = n >> 7, d = n & 127;
        ushort4 u;
        u.x = f2bu(acc[mt][nt][0]);
        u.y = f2bu(acc[mt][nt][1]);
        u.z = f2bu(acc[mt][nt][2]);
        u.w = f2bu(acc[mt][nt][3]);
        *(ushort4*)&o[((size_t)((bb * 16 + hh) * 128 + d) << 11) + t] = u;
      }
    }
  }
}

// ---------------------------------------------------------------------------
// 128x256 2-phase-per-K-tile pipelined GEMM (verified R11 structure) —
// used for the OUT-PROJECTION only (OMODE 1, NTPX 1, grid 256 = 1 round).
// ---------------------------------------------------------------------------
template <int OMODE, int NTPX>
__global__ __launch_bounds__(512, 2)
void gemm_pipe(const u16* __restrict__ A, const u16* __restrict__ BT,
               void* __restrict__ C, u16* __restrict__ C2) {
  __shared__ __align__(16) u16 As[3][2][128][32];   // 48KB, A full-tile ring
  __shared__ __align__(16) u16 Bs[6][2][128][32];   // 96KB, B half-tile ring

  const int tid = threadIdx.x;
  const int w = tid >> 6;
  const int lane = tid & 63;
  const int wm = w >> 2;
  const int wn = w & 3;
  const int wh = wn >> 1;
  const int li = lane & 15, lh = lane >> 4;
  const int lhx8 = (lh ^ (((li >> 3) & 1) << 1)) * 8;
  const int brow = (wn & 1) * 64;

  const int bid = blockIdx.x;
  const int xcd = bid & 7;
  const int local = bid >> 3;
  const int mtile = local / NTPX;
  const int ntile = xcd * NTPX + (local % NTPX);
  const int m0 = mtile * 128, n0 = ntile * 256;

  const int o = tid << 4;
  const int osz = o ^ (((o >> 9) & 1) << 5);
  const int srow = osz >> 6;
  const int skel = (osz & 63) >> 1;
  const size_t soff = ((size_t)srow * 2048 + skel) * 2;

  const char* pA  = (const char*)A  + (size_t)m0 * 4096 + soff;
  const char* pB0 = (const char*)BT + (size_t)n0 * 4096 + soff;
  const char* pB1 = pB0 + (size_t)128 * 4096;

#define STAGE_A(SLOT)    { stage2(pA,  (char*)As + (SLOT) * 16384 + w * 1024); pA  += 128; }
#define STAGE_BODD(SLOT) { stage2(pB1, (char*)Bs + (SLOT) * 16384 + w * 1024); pB1 += 128; }
#define STAGE_BEVEN(SLOT){ stage2(pB0, (char*)Bs + (SLOT) * 16384 + w * 1024); pB0 += 128; }

  const f32x4 fzero = {0.f, 0.f, 0.f, 0.f};
  f32x4 acc[4][4];
#pragma unroll
  for (int i = 0; i < 4; ++i)
#pragma unroll
    for (int jj = 0; jj < 4; ++jj) acc[i][jj] = fzero;

  STAGE_A(0); STAGE_BEVEN(0); STAGE_BODD(1); STAGE_A(1); STAGE_BEVEN(2);
  asm volatile("s_waitcnt vmcnt(3)" ::: "memory");
  __builtin_amdgcn_s_barrier();
  asm volatile("" ::: "memory");

#define QPHASE(SA, SB2, KSI, STAGES, TAIL)                                     \
  {                                                                            \
    bf16x8 af[4], bfc[4];                                                      \
    _Pragma("unroll")                                                          \
    for (int mq = 0; mq < 4; ++mq)                                             \
      af[mq] = *(const bf16x8*)&As[(SA)][(KSI)][wm * 64 + mq * 16 + li][lhx8]; \
    _Pragma("unroll")                                                          \
    for (int nt = 0; nt < 4; ++nt)                                             \
      bfc[nt] = *(const bf16x8*)&Bs[(SB2) + wh][(KSI)][brow + nt * 16 + li][lhx8]; \
    STAGES;                                                                    \
    __builtin_amdgcn_s_barrier();                                              \
    asm volatile("" ::: "memory");                                             \
    __builtin_amdgcn_s_setprio(1);                                             \
    _Pragma("unroll")                                                          \
    for (int mq = 0; mq < 4; ++mq) {                                           \
      _Pragma("unroll")                                                        \
      for (int nt = 0; nt < 4; ++nt)                                           \
        acc[mq][nt] = __builtin_amdgcn_mfma_f32_16x16x32_bf16(                 \
            af[mq], bfc[nt], acc[mq][nt], 0, 0, 0);                            \
    }                                                                          \
    __builtin_amdgcn_s_setprio(0);                                             \
    TAIL;                                                                      \
    __builtin_amdgcn_s_barrier();                                              \
    asm volatile("" ::: "memory");                                             \
  }

#define TILE_MAIN(U)                                                           \
  QPHASE((U), 2 * (U), 0,                                                      \
         { STAGE_A(((U) + 2) % 3); STAGE_BODD((2 * (U) + 3) % 6); }, ((void)0)) \
  QPHASE((U), 2 * (U), 1, { STAGE_BEVEN((2 * (U) + 4) % 6); },                 \
         asm volatile("s_waitcnt vmcnt(2)" ::: "memory"))

  for (int t3 = 0; t3 < 10; ++t3) {
    TILE_MAIN(0)
    TILE_MAIN(1)
    TILE_MAIN(2)
  }
  QPHASE(0, 0, 0, { STAGE_BODD(3); }, ((void)0))
  QPHASE(0, 0, 1, ((void)0), asm volatile("s_waitcnt vmcnt(0)" ::: "memory"))
  QPHASE(1, 2, 0, ((void)0), ((void)0))
  QPHASE(1, 2, 1, ((void)0), ((void)0))

#undef QPHASE
#undef TILE_MAIN
#undef STAGE_A
#undef STAGE_BODD
#undef STAGE_BEVEN

  const int nB0 = (OMODE == 0 ? (n0 & 2047) : n0) + wn * 64;
  const int mB = m0 + wm * 64;
  const int proj = n0 >> 11;
#pragma unroll
  for (int mt = 0; mt < 4; ++mt) {
#pragma unroll
    for (int nt = 0; nt < 4; ++nt) {
      const int mb = mB + mt * 16 + lh * 4;
      const int n = nB0 + nt * 16 + li;
      if (OMODE == 1) {
        float* o = (float*)C;
#pragma unroll
        for (int r = 0; r < 4; ++r)
          o[(size_t)(mb + r) * 2048 + n] = acc[mt][nt][r];
      } else if (proj < 2) {
        u16* o = (u16*)C + (size_t)proj * 4096 * 2048;
#pragma unroll
        for (int r = 0; r < 4; ++r)
          o[(size_t)(mb + r) * 2048 + n] = f2bu(acc[mt][nt][r]);
      } else {
        const int bb = mb >> 11, t = mb & 2047;
        const int hh = n >> 7, d = n & 127;
        ushort4 u;
        u.x = f2bu(acc[mt][nt][0]);
        u.y = f2bu(acc[mt][nt][1]);
        u.z = f2bu(acc[mt][nt][2]);
        u.w = f2bu(acc[mt][nt][3]);
        *(ushort4*)&C2[((size_t)((bb * 16 + hh) * 128 + d) << 11) + t] = u;
      }
    }
  }
}

// ---------------------------------------------------------------------------
// R14 fused-QKV GEMM: 128x256 tile, BK=32, ONE phase per K-step, 72KB LDS
// -> 2 blocks/CU. A(4096,2048) @ BT(6144,2048)^T, grid 768 (NTPX=3).
//   A ring: 3 x 8KB [128][32], slot j%3.  B ring: 3 x 16KB [256][32].
//   Phase j: read slot j%3 (4 A-frag + 4 B-frag b128/wave); stage (j+2)
//   -> slot (j+2)%3 (A 1 + B 2 instrs/wave); barrier; 16 MFMA; vmcnt(3)
//   tail (confirms j+1's 3, leaves j+2's 3 in flight); barrier.
//   Slot safety: stage target != phase-j read slot and != phase-j+1 read
//   slot; occupant (j-1) fully read before phase j-1's closing barrier.
//   Tail: j=62 no stage + vmcnt(0); j=63 clean.
// ---------------------------------------------------------------------------
__global__ __launch_bounds__(512, 4)
void gemm_qkv2(const u16* __restrict__ A, const u16* __restrict__ BT,
               u16* __restrict__ C, u16* __restrict__ C2) {
  __shared__ __align__(16) u16 As[3][128][32];   // 24KB
  __shared__ __align__(16) u16 Bs[3][256][32];   // 48KB

  const int tid = threadIdx.x;
  const int lane = tid & 63;
  const int w = tid >> 6;              // 0..7
  const int wm = w >> 2;               // M-half (64 rows of 128)
  const int wn = w & 3;                // N quarter (64 cols of 256)
  const int li = lane & 15, lh = lane >> 4;
  const int lhx8 = (lh ^ (((li >> 3) & 1) << 1)) * 8;   // swizzled k-chunk

  // XCD-aware swizzle: xcd owns ntiles [3*xcd, 3*xcd+2], mt-major inside.
  const int bid = blockIdx.x;          // 0..767
  const int xcd = bid & 7;
  const int local = bid >> 3;          // 0..95
  const int mtile = local / 3;         // 0..31
  const int ntile = xcd * 3 + (local % 3);
  const int m0 = mtile * 128, n0 = ntile * 256;

  // per-lane staging source offset (st_16x32 pre-swizzle on 8KB image)
  const int o = tid << 4;
  const int osz = o ^ (((o >> 9) & 1) << 5);
  const int srow = osz >> 6;                       // 0..127
  const int skel = (osz & 63) >> 1;
  const size_t soff = ((size_t)srow * 2048 + skel) * 2;  // bytes

  const char* pA = (const char*)A  + (size_t)m0 * 4096 + soff;
  const char* pB = (const char*)BT + (size_t)n0 * 4096 + soff;

#define STA(SLOT) { stage16(pA, (char*)As + (SLOT) * 8192 + w * 1024, lane); pA += 64; }
#define STB(SLOT) { stageK(pB, (char*)Bs + (SLOT) * 16384 + w * 1024); pB += 64; }

  const f32x4 fzero = {0.f, 0.f, 0.f, 0.f};
  f32x4 acc[4][4];
#pragma unroll
  for (int i = 0; i < 4; ++i)
#pragma unroll
    for (int jj = 0; jj < 4; ++jj) acc[i][jj] = fzero;

  // prologue: {A0,B0}=3 instrs, {A1,B1}=3. vmcnt(3) confirms K-step 0.
  STA(0); STB(0); STA(1); STB(1);
  asm volatile("s_waitcnt vmcnt(3)" ::: "memory");
  __builtin_amdgcn_s_barrier();
  asm volatile("" ::: "memory");

#define QP2(SLOT, STAGES, TAIL)                                                \
  {                                                                            \
    bf16x8 af[4], bfc[4];                                                      \
    _Pragma("unroll")                                                          \
    for (int mq = 0; mq < 4; ++mq)                                             \
      af[mq] = *(const bf16x8*)&As[(SLOT)][wm * 64 + mq * 16 + li][lhx8];      \
    _Pragma("unroll")                                                          \
    for (int nt = 0; nt < 4; ++nt)                                             \
      bfc[nt] = *(const bf16x8*)&Bs[(SLOT)][wn * 64 + nt * 16 + li][lhx8];     \
    STAGES;                                                                    \
    __builtin_amdgcn_s_barrier();                                              \
    asm volatile("" ::: "memory");                                             \
    __builtin_amdgcn_s_setprio(1);                                             \
    _Pragma("unroll")                                                          \
    for (int mq = 0; mq < 4; ++mq) {                                           \
      _Pragma("unroll")                                                        \
      for (int nt = 0; nt < 4; ++nt)                                           \
        acc[mq][nt] = __builtin_amdgcn_mfma_f32_16x16x32_bf16(                 \
            af[mq], bfc[nt], acc[mq][nt], 0, 0, 0);                            \
    }                                                                          \
    __builtin_amdgcn_s_setprio(0);                                             \
    TAIL;                                                                      \
    __builtin_amdgcn_s_barrier();                                              \
    asm volatile("" ::: "memory");                                             \
  }

#define VM3 asm volatile("s_waitcnt vmcnt(3)" ::: "memory")

  for (int t3 = 0; t3 < 20; ++t3) {   // K-steps 0..59
    QP2(0, { STA(2); STB(2); }, VM3);
    QP2(1, { STA(0); STB(0); }, VM3);
    QP2(2, { STA(1); STB(1); }, VM3);
  }
  QP2(0, { STA(2); STB(2); }, VM3);                                   // j=60
  QP2(1, { STA(0); STB(0); }, VM3);                                   // j=61
  QP2(2, ((void)0), asm volatile("s_waitcnt vmcnt(0)" ::: "memory")); // j=62
  QP2(0, ((void)0), ((void)0));                                       // j=63

#undef QP2
#undef VM3
#undef STA
#undef STB

  // epilogue: C/D layout col = lane&15, row = (lane>>4)*4 + reg
  const int proj = n0 >> 11;                 // 0=Q, 1=K, 2=V (block-uniform)
  const int nB = (n0 & 2047) + wn * 64;
  const int mB = m0 + wm * 64;
#pragma unroll
  for (int mt = 0; mt < 4; ++mt) {
#pragma unroll
    for (int nt = 0; nt < 4; ++nt) {
      const int mb = mB + mt * 16 + lh * 4;
      const int n = nB + nt * 16 + li;
      if (proj < 2) {
        u16* o = C + (size_t)proj * 4096 * 2048;
#pragma unroll
        for (int r = 0; r < 4; ++r)
          o[(size_t)(mb + r) * 2048 + n] = f2bu(acc[mt][nt][r]);
      } else {
        const int bb = mb >> 11, t = mb & 2047;
        const int hh = n >> 7, d = n & 127;
        ushort4 u;
        u.x = f2bu(acc[mt][nt][0]);
        u.y = f2bu(acc[mt][nt][1]);
        u.z = f2bu(acc[mt][nt][2]);
        u.w = f2bu(acc[mt][nt][3]);
        *(ushort4*)&C2[((size_t)((bb * 16 + hh) * 128 + d) << 11) + t] = u;
      }
    }
  }
}

// ---------------------------------------------------------------------------
// Flash differential attention (unchanged, verified).
// ---------------------------------------------------------------------------
__device__ __forceinline__ void stage_kv(const u16* __restrict__ kbase,
                                         const u16* __restrict__ vbase, int j,
                                         u16* ksBuf, u16* vsBuf, int w, int lane) {
  const int kst_r = lane >> 4, kst_c = lane & 15;
  const int vst_r = lane >> 3, vst_c = lane & 7;
#pragma unroll
  for (int i = 0; i < 4; ++i) {
    const int t = w * 4 + i;
    const int srow = t * 4 + kst_r;
    const int scb = kst_c ^ (srow & 7);
    stage16(kbase + (size_t)(j * 64 + srow) * 2048 + scb * 8,
            (char*)ksBuf + t * 1024, lane);
    const int drow = t * 8 + vst_r;
    const int dcb = vst_c ^ (drow & 7);
    stage16(vbase + (size_t)drow * 2048 + j * 64 + dcb * 8,
            (char*)vsBuf + t * 1024, lane);
  }
}

__global__ __launch_bounds__(256, 2)
void diff_attn(const u16* __restrict__ Q, const u16* __restrict__ K,
               const u16* __restrict__ VT, const float* __restrict__ lamin,
               u16* __restrict__ AO) {
  __shared__ __align__(16) u16 Ks[2][64 * 128];
  __shared__ __align__(16) u16 Vs[2][128 * 64];
  __shared__ __align__(16) u16 Ps1[64 * 64];
  __shared__ __align__(16) u16 Ps2[64 * 64];

  const int tid = threadIdx.x, lane = tid & 63, w = tid >> 6;
  const int li = lane & 15, lh = lane >> 4;
  const int bh = blockIdx.x & 31, pair = blockIdx.x >> 5;
  const int b = bh >> 4, h = bh & 15;

  const float lam = 1.f / (1.f + exp2f(-lamin[h] * LOG2E));
  const u16* kbase = K + ((size_t)(b * 2048)) * 2048 + h * 128;
  const u16* vbase = VT + ((size_t)(b * 16 + h) << 18);
  const f32x4 fzero = {0.f, 0.f, 0.f, 0.f};

  for (int phase = 0; phase < 2; ++phase) {
    const int it = phase ? 31 - pair : pair;
    const int t0 = it * 64;

    bf16x8 qf[4];
    {
      const u16* qp = Q + (size_t)(b * 2048 + t0 + w * 16 + li) * 2048 + h * 128 + lh * 8;
#pragma unroll
      for (int kk = 0; kk < 4; ++kk) qf[kk] = *(const bf16x8*)(qp + kk * 32);
    }

    f32x4 o1[8], o2[8];
#pragma unroll
    for (int i = 0; i < 8; ++i) { o1[i] = fzero; o2[i] = fzero; }
    float l1p[4] = {0.f, 0.f, 0.f, 0.f};
    float l2p[4] = {0.f, 0.f, 0.f, 0.f};

    if (phase) __syncthreads();
    stage_kv(kbase, vbase, 0, Ks[0], Vs[0], w, lane);

    for (int j = 0; j <= it; ++j) {
      const int cur = j & 1;
      __syncthreads();
      if (j < it)
        stage_kv(kbase, vbase, j + 1, Ks[cur ^ 1], Vs[cur ^ 1], w, lane);

      const u16* __restrict__ ks = Ks[cur];
      const u16* __restrict__ vs = Vs[cur];
      const bool diag = (j == it);

#pragma unroll
      for (int nt = 0; nt < 4; ++nt) {
        const int srow = nt * 16 + li;
        const int sw = li & 7;
        bf16x8 b0 = *(const bf16x8*)&ks[srow * 128 + ((0 + lh) ^ sw) * 8];
        bf16x8 b1 = *(const bf16x8*)&ks[srow * 128 + ((4 + lh) ^ sw) * 8];
        bf16x8 b2 = *(const bf16x8*)&ks[srow * 128 + ((8 + lh) ^ sw) * 8];
        bf16x8 b3 = *(const bf16x8*)&ks[srow * 128 + ((12 + lh) ^ sw) * 8];
        f32x4 s1 = fzero, s2 = fzero;
        s1 = __builtin_amdgcn_mfma_f32_16x16x32_bf16(qf[0], b0, s1, 0, 0, 0);
        s1 = __builtin_amdgcn_mfma_f32_16x16x32_bf16(qf[1], b1, s1, 0, 0, 0);
        s2 = __builtin_amdgcn_mfma_f32_16x16x32_bf16(qf[2], b2, s2, 0, 0, 0);
        s2 = __builtin_amdgcn_mfma_f32_16x16x32_bf16(qf[3], b3, s2, 0, 0, 0);

        const int cb = nt * 2 + (li >> 3);
        const int sg = j * 64 + nt * 16 + li;
#pragma unroll
        for (int r = 0; r < 4; ++r) {
          const int row = w * 16 + lh * 4 + r;
          float p1, p2;
          if (diag && sg > t0 + row) {
            p1 = 0.f; p2 = 0.f;
          } else {
            p1 = exp2f(fmaf(s1[r], KS, -CB));
            p2 = exp2f(fmaf(s2[r], KS, -CB));
          }
          l1p[r] += p1; l2p[r] += p2;
          const int idx = row * 64 + ((cb ^ (row & 7)) << 3) + (li & 7);
          Ps1[idx] = f2bu(p1);
          Ps2[idx] = f2bu(p2);
        }
      }

#pragma unroll
      for (int kss = 0; kss < 2; ++kss) {
        const int arow = w * 16 + li;
        const int jb = ((kss * 4 + lh) ^ (li & 7)) * 8;
        bf16x8 a1f = *(const bf16x8*)&Ps1[arow * 64 + jb];
        bf16x8 a2f = *(const bf16x8*)&Ps2[arow * 64 + jb];
#pragma unroll
        for (int nt = 0; nt < 8; ++nt) {
          const int d = nt * 16 + li;
          bf16x8 vf = *(const bf16x8*)&vs[d * 64 + ((kss * 4 + lh) ^ (li & 7)) * 8];
          o1[nt] = __builtin_amdgcn_mfma_f32_16x16x32_bf16(a1f, vf, o1[nt], 0, 0, 0);
          o2[nt] = __builtin_amdgcn_mfma_f32_16x16x32_bf16(a2f, vf, o2[nt], 0, 0, 0);
        }
      }
    }

#pragma unroll
    for (int r = 0; r < 4; ++r) {
#pragma unroll
      for (int off = 1; off < 16; off <<= 1) {
        l1p[r] += __shfl_xor(l1p[r], off);
        l2p[r] += __shfl_xor(l2p[r], off);
      }
    }

#pragma unroll
    for (int r = 0; r < 4; ++r) {
      const float inv1 = 1.f / l1p[r];
      const float inv2 = lam / l2p[r];
      u16* orow = AO + (size_t)(b * 2048 + t0 + w * 16 + lh * 4 + r) * 2048 + h * 128 + li;
#pragma unroll
      for (int nt = 0; nt < 8; ++nt)
        orow[nt * 16] = f2bu(o1[nt][r] * inv1 - o2[nt][r] * inv2);
    }
  }
}

// ---------------------------------------------------------------------------
extern "C" void kernel_launch(void* const* d_in, const int* in_sizes, int n_in,
                              void* d_out, int out_size, void* d_ws, size_t ws_size,
                              hipStream_t stream) {
  const float* x   = (const float*)d_in[0];
  const float* Wq  = (const float*)d_in[1];
  const float* Wk  = (const float*)d_in[2];
  const float* Wv  = (const float*)d_in[3];
  const float* Wo  = (const float*)d_in[4];
  const float* lam = (const float*)d_in[5];
  float* out = (float*)d_out;

  const size_t MB = 1ull << 20;
  char* ws = (char*)d_ws;
  u16* qb = (u16*)d_out;            // 16 MB scratch inside d_out (rewritten at end)
  u16* kb = qb + (size_t)4096 * 2048;

  if (ws_size >= 56 * MB) {
    // ---- fused-QKV path ----
    u16* xb = (u16*)(ws);             // 16 MB: x bf16; later AO
    u16* wT = (u16*)(ws + 16 * MB);   // 24 MB: [WqT|WkT|WvT]; later WoT (8MB)
    u16* vt = (u16*)(ws + 40 * MB);   // 16 MB: V^T per head (b,h,d,t)
    u16* ao = xb;

    f32_to_bf16_k<<<8192, 256, 0, stream>>>(x, xb, 2097152);
    transpose3_f32_bf16<<<dim3(64, 64, 3), 256, 0, stream>>>(Wq, Wk, Wv, wT);
    // fused QKV, BK=32 single-phase K-steps, 72KB LDS -> 2 blocks/CU
    gemm_qkv2<<<dim3(768), 512, 0, stream>>>(xb, wT, qb, vt);

    diff_attn<<<dim3(512), 256, 0, stream>>>(qb, kb, vt, lam, ao);

    transpose_f32_bf16<<<dim3(64, 64), 256, 0, stream>>>(Wo, wT, 2048, 2048);
    gemm_pipe<1, 1><<<dim3(256), 512, 0, stream>>>(ao, wT, out, nullptr);
  } else {
    // ---- fallback: R5 sequence (40 MB scratch) ----
    u16* xb = (u16*)(ws);
    u16* wT = (u16*)(ws + 16 * MB);
    u16* vt = (u16*)(ws + 24 * MB);
    u16* ao = xb;

    f32_to_bf16_k<<<8192, 256, 0, stream>>>(x, xb, 2097152);
    transpose_f32_bf16<<<dim3(64, 64), 256, 0, stream>>>(Wq, wT, 2048, 2048);
    gemm_bt<0><<<dim3(32, 16), 256, 0, stream>>>(xb, wT, qb, nullptr, 4096, 2048, 2048);
    transpose_f32_bf16<<<dim3(64, 64), 256, 0, stream>>>(Wk, wT, 2048, 2048);
    gemm_bt<0><<<dim3(32, 16), 256, 0, stream>>>(xb, wT, kb, nullptr, 4096, 2048, 2048);
    transpose_f32_bf16<<<dim3(64, 64), 256, 0, stream>>>(Wv, wT, 2048, 2048);
    gemm_bt<2><<<dim3(32, 16), 256, 0, stream>>>(xb, wT, vt, nullptr, 4096, 2048, 2048);

    diff_attn<<<dim3(512), 256, 0, stream>>>(qb, kb, vt, lam, ao);

    transpose_f32_bf16<<<dim3(64, 64), 256, 0, stream>>>(Wo, wT, 2048, 2048);
    gemm_bt<1><<<dim3(32, 16), 256, 0, stream>>>(ao, wT, out, nullptr, 4096, 2048, 2048);
  }
}